// Round 22
// baseline (470.362 us; speedup 1.0000x reference)
//
#include <hip/hip_runtime.h>
#include <stdint.h>

#define TB     400
#define OUTROW 160000   // T * 2F

typedef _Float16 half2_t __attribute__((ext_vector_type(2)));
typedef _Float16 f16x8 __attribute__((ext_vector_type(8)));
typedef float    f32x4 __attribute__((ext_vector_type(4)));
typedef uint16_t u16;
typedef uint32_t u32;

__device__ __forceinline__ float sigf(float x){ return 1.0f/(1.0f+__expf(-x)); }
__device__ __forceinline__ float tanhf_(float x){ float e=__expf(2.0f*x); return 1.0f-2.0f/(e+1.0f); }
__device__ __forceinline__ u16 h16(float x){ _Float16 h=(_Float16)x; return __builtin_bit_cast(u16,h); }
__device__ __forceinline__ u32 pk2(float a, float b){ return (u32)h16(a) | ((u32)h16(b)<<16); }
__device__ __forceinline__ float f16f(u16 u){ return (float)__builtin_bit_cast(_Float16,u); }

// ---------- k_prep: blocks 0..103 compute Qp (= P @ W_m, f16 pairs); 104..359 compute M0W ----
__global__ __launch_bounds__(512)
void k_prep(const float* __restrict__ Wf, const float* __restrict__ Pf,
            const float* __restrict__ Wb, const float* __restrict__ Pb,
            const float* __restrict__ m0f, const float* __restrict__ m0b,
            u32* __restrict__ Qp, float* __restrict__ M0W)
{
  const int b = blockIdx.x, tid = threadIdx.x;
  if (b < 104){
    const int dir = b/52, j = b%52;
    const float* W = dir?Wb:Wf; const float* P = dir?Pb:Pf;
    __shared__ float pr[2][200];
    for (int i=tid;i<400;i+=512){ int u=i/200,k=i%200; int hk=2*j+u;
      pr[u][k] = (hk<100)? P[(size_t)hk*200+k] : 0.f; }
    __syncthreads();
    if (tid<400){
      float a0=0.f,a1=0.f;
      for (int k=0;k<200;++k){ float w = W[(size_t)(100+k)*400+tid]; a0 += pr[0][k]*w; a1 += pr[1][k]*w; }
      Qp[(size_t)(dir*52+j)*400+tid] = pk2(a0,a1);
    }
  } else {
    const int bb2 = b-104, dir = bb2>>7, seq = bb2&127;
    const float* m0 = dir?m0b:m0f; const float* W = dir?Wb:Wf;
    __shared__ float mr[200];
    if (tid<200) mr[tid] = m0[(size_t)seq*200+tid];
    __syncthreads();
    if (tid<400){
      float a=0.f;
      for (int k=0;k<200;++k) a += mr[k]*W[(size_t)(100+k)*400+tid];
      M0W[(size_t)bb2*400+tid] = a;
    }
  }
}

// ---------- k_g4: G = f16(x@Wx + bias(+1 f) [+ m0@Wm @ first t]) via MFMA (proven) ----------
__global__ __launch_bounds__(512, 1)
void k_g4(const float* __restrict__ z,
          const float* __restrict__ Wf, const float* __restrict__ bf,
          const float* __restrict__ Wb, const float* __restrict__ bb,
          const float* __restrict__ M0W, u16* __restrict__ Gh)
{
  __shared__ __align__(16) u16 xa[5][4][512];   // 5 M-tiles x 4 K-tiles, 20 KB
  const int tid = threadIdx.x, wv = tid>>6, lane = tid&63;
  const int l15 = lane&15, lg = lane>>4;
  const int dir = blockIdx.x>>7, seq = blockIdx.x&127;
  const float* W  = dir?Wb:Wf;
  const float* bv = dir?bb:bf;

  const int nnt = (wv==0)?4:3;
  const int ntl[4] = {wv, wv+8, wv+16, 24};

  f16x8 wb_[4][4];
  float bias[4], m0w[4];
  #pragma unroll
  for (int i=0;i<4;++i) if (i<nnt){
    const int col = ntl[i]*16 + l15;
    #pragma unroll
    for (int kt=0;kt<4;++kt){
      f16x8 v;
      #pragma unroll
      for (int e=0;e<8;++e){
        int k = kt*32 + lg*8 + e;
        v[e] = (_Float16)((k<100)? W[(size_t)k*400+col] : 0.f);
      }
      wb_[i][kt]=v;
    }
    bias[i] = bv[col] + (((col/100)==2)?1.0f:0.0f);
    m0w[i]  = M0W[(size_t)(dir*128+seq)*400 + col];
  }
  const int tfirst = dir?(TB-1):0;

  for (int i=tid;i<10240;i+=512) ((u16*)xa)[i] = (u16)0;
  __syncthreads();

  for (int chunk=0; chunk<5; ++chunk){
    for (int i=tid;i<8000;i+=512){
      int r = i/100, k = i%100;
      int t = chunk*80 + r;
      float v = z[(size_t)seq*40000 + (size_t)t*100 + k];
      int mt = r>>4, m = r&15, kt = k>>5, kk = k&31;
      xa[mt][kt][(m|((kk>>3)<<4))*8 + (kk&7)] = h16(v);
    }
    __syncthreads();
    #pragma unroll
    for (int mt=0; mt<5; ++mt){
      f16x8 af[4];
      #pragma unroll
      for (int kt=0;kt<4;++kt)
        af[kt] = *reinterpret_cast<const f16x8*>(&xa[mt][kt][lane*8]);
      #pragma unroll
      for (int i=0;i<4;++i) if (i<nnt){
        f32x4 acc = {0.f,0.f,0.f,0.f};
        #pragma unroll
        for (int kt=0;kt<4;++kt)
          acc = __builtin_amdgcn_mfma_f32_16x16x32_f16(af[kt], wb_[i][kt], acc, 0,0,0);
        const int col = ntl[i]*16 + l15;
        #pragma unroll
        for (int r=0;r<4;++r){
          int t = chunk*80 + mt*16 + lg*4 + r;
          float gv = acc[r] + bias[i] + ((t==tfirst)? m0w[i] : 0.f);
          Gh[((size_t)dir*51200 + (size_t)seq*400 + t)*400 + col] = h16(gv);
        }
      }
    }
    __syncthreads();
  }
}

// ---------- k_recm: recurrence on the MATRIX pipe. M=1 MFMA with replicated A-rows. ----------
// A-frag: lane reads h[kt*32 + (lane>>4)*8 .. +8) -> all 16 rows identical valid dots;
// every lane ends with D for col = nt*16 + (lane&15) in acc[0]. B-frags (Q,P) AGPR-resident.
__global__ __launch_bounds__(512, 1)
void k_recm(const float* __restrict__ c0f, const float* __restrict__ c0b,
            const float* __restrict__ Pf, const float* __restrict__ Pb,
            const u32* __restrict__ Qp, const u16* __restrict__ Gh,
            float* __restrict__ out)
{
  __shared__ __align__(16) u16 h2[2][128];  // double-buffered h (f16), k 100..127 = 0
  __shared__ float ga[400];                 // activated gates
  const int tid = threadIdx.x, wv = tid>>6, lane = tid&63;
  const int l15 = lane&15, lg = lane>>4;
  const int dir = blockIdx.x>>7, seq = blockIdx.x&127;
  const float* c0 = dir?c0b:c0f;
  const float* P  = dir?Pb:Pf;

  // gates tiles: wave w -> {w, w+8, w+16} (+24 for w==0); proj tiles: w>=1 -> {2(w-1), +1} (w7: 1)
  const int ngt = (wv==0)?4:3;
  const int gnt[4] = {wv, wv+8, wv+16, 24};
  const int npt = (wv==0)?0:((wv==7)?1:2);
  const int pnt0 = 2*(wv-1);

  // ---- stage gate B-frags from Qp (f16 pair-packed; pair-rows 50,51 are zero; k>=104 -> 0) ----
  f16x8 qb[4][4];
  int   gcol[4]; int ggate[4];
  #pragma unroll
  for (int i=0;i<4;++i) if (i<ngt){
    const int col = gnt[i]*16 + l15;
    gcol[i] = col; ggate[i] = col/100;
    #pragma unroll
    for (int kt=0;kt<4;++kt){
      f16x8 v;
      #pragma unroll
      for (int e=0;e<8;++e){
        int k = kt*32 + lg*8 + e;
        u16 q = 0;
        if (k < 104){
          u32 pr = Qp[(size_t)(dir*52 + (k>>1))*400 + col];
          q = (k&1) ? (u16)(pr>>16) : (u16)(pr&0xffff);
        }
        v[e] = __builtin_bit_cast(_Float16, q);
      }
      qb[i][kt]=v;
    }
  }
  // ---- stage proj B-frags from P (f32; k>=100 or col>=200 -> 0) ----
  f16x8 pb[2][4];
  int pcol[2];
  #pragma unroll
  for (int i=0;i<2;++i) if (i<npt){
    const int col = (pnt0+i)*16 + l15;
    pcol[i] = col;
    #pragma unroll
    for (int kt=0;kt<4;++kt){
      f16x8 v;
      #pragma unroll
      for (int e=0;e<8;++e){
        int k = kt*32 + lg*8 + e;
        v[e] = (_Float16)((k<100 && col<200)? P[(size_t)k*200+col] : 0.f);
      }
      pb[i][kt]=v;
    }
  }

  float cs = 0.f;
  if (tid < 100) cs = c0[(size_t)seq*100 + tid];
  if (tid < 128) ((u32*)h2)[tid] = 0u;      // zero both h buffers (h(-1)=0 + permanent pads)
  __syncthreads();

  const size_t gb = ((size_t)dir*51200 + (size_t)seq*400)*400;
  u16 gn[4] = {0,0,0,0};
  {
    const int tt0 = dir?(TB-1):0;
    #pragma unroll
    for (int i=0;i<4;++i) if (i<ngt) gn[i] = Gh[gb + (size_t)tt0*400 + gcol[i]];
  }

  for (int t=0; t<=TB; ++t){
    const int p = t&1;                      // h2[p] = h(t-1)
    // A-frags: broadcast reads of h(t-1), replicated-row layout
    f16x8 af[4];
    #pragma unroll
    for (int kt=0;kt<4;++kt)
      af[kt] = *reinterpret_cast<const f16x8*>(&h2[p][kt*32 + lg*8]);

    if (t < TB){
      u16 gc[4];
      #pragma unroll
      for (int i=0;i<4;++i) gc[i] = gn[i];
      if (t+1 < TB){
        const int tn = dir?(TB-2-t):(t+1);
        #pragma unroll
        for (int i=0;i<4;++i) if (i<ngt) gn[i] = Gh[gb + (size_t)tn*400 + gcol[i]];
      }
      #pragma unroll
      for (int i=0;i<4;++i) if (i<ngt){
        f32x4 acc = {0.f,0.f,0.f,0.f};
        #pragma unroll
        for (int kt=0;kt<4;++kt)
          acc = __builtin_amdgcn_mfma_f32_16x16x32_f16(af[kt], qb[i][kt], acc, 0,0,0);
        float a = acc[0] + f16f(gc[i]);     // every lane: full dot for col gcol[i]
        float arg = (ggate[i]==1) ? a+a : a;     // tanh(x)=2*sig(2x)-1
        float v = sigf(arg);
        float act = (ggate[i]==1) ? 2.0f*v-1.0f : v;
        if (lg==0) ga[gcol[i]] = act;
      }
    }
    if (t >= 1){
      const int ttp = dir ? (TB-t) : (t-1); // output slot of step t-1
      #pragma unroll
      for (int i=0;i<2;++i) if (i<npt){
        f32x4 acc = {0.f,0.f,0.f,0.f};
        #pragma unroll
        for (int kt=0;kt<4;++kt)
          acc = __builtin_amdgcn_mfma_f32_16x16x32_f16(af[kt], pb[i][kt], acc, 0,0,0);
        if (lg==0 && pcol[i]<200)
          __builtin_nontemporal_store(acc[0],
              out + (size_t)seq*OUTROW + (size_t)ttp*400 + dir*200 + pcol[i]);
      }
    }
    __syncthreads();                        // 1: ga ready; af consumed
    if (tid < 100 && t < TB){
      float I=ga[tid], J=ga[100+tid], F=ga[200+tid], O=ga[300+tid];
      float cc = F*cs + I*J; cs = cc;
      float h = O*tanhf_(cc);
      h2[p^1][tid] = h16(h);
    }
    __syncthreads();                        // 2: h(t) ready
  }
}

extern "C" void kernel_launch(void* const* d_in, const int* in_sizes, int n_in,
                              void* d_out, int out_size, void* d_ws, size_t ws_size,
                              hipStream_t stream) {
  (void)in_sizes; (void)n_in; (void)out_size; (void)ws_size;
  const float* z   = (const float*)d_in[0];
  const float* c0f = (const float*)d_in[1];
  const float* m0f = (const float*)d_in[2];
  const float* c0b = (const float*)d_in[3];
  const float* m0b = (const float*)d_in[4];
  const float* Wf  = (const float*)d_in[5];
  const float* bf  = (const float*)d_in[6];
  const float* Pf  = (const float*)d_in[7];
  const float* Wb  = (const float*)d_in[8];
  const float* bb  = (const float*)d_in[9];
  const float* Pb  = (const float*)d_in[10];

  u32*   Qp  = (u32*)d_ws;                            // 166,400 B
  float* M0W = (float*)((char*)d_ws + 196608);        // 409,600 B
  u16*   Gh  = (u16*)((char*)d_ws + 655360);          // 81,920,000 B (total ~82.6 MB)

  k_prep<<<360, 512, 0, stream>>>(Wf, Pf, Wb, Pb, m0f, m0b, Qp, M0W);
  k_g4  <<<256, 512, 0, stream>>>(z, Wf, bf, Wb, bb, M0W, Gh);
  k_recm<<<256, 512, 0, stream>>>(c0f, c0b, Pf, Pb, Qp, Gh, (float*)d_out);
}

// Round 23
// 323.121 us; speedup vs baseline: 1.4557x; 1.4557x over previous
//
#include <hip/hip_runtime.h>
#include <stdint.h>

#define TB     400
#define OUTROW 160000   // T * 2F

typedef _Float16 half2_t __attribute__((ext_vector_type(2)));
typedef _Float16 f16x8 __attribute__((ext_vector_type(8)));
typedef float    f32x4 __attribute__((ext_vector_type(4)));
typedef uint16_t u16;
typedef uint32_t u32;

__device__ __forceinline__ float sigf(float x){ return 1.0f/(1.0f+__expf(-x)); }
__device__ __forceinline__ float tanhf_(float x){ float e=__expf(2.0f*x); return 1.0f-2.0f/(e+1.0f); }
__device__ __forceinline__ u16 h16(float x){ _Float16 h=(_Float16)x; return __builtin_bit_cast(u16,h); }
__device__ __forceinline__ u32 pk2(float a, float b){ return (u32)h16(a) | ((u32)h16(b)<<16); }
__device__ __forceinline__ float f16f(u16 u){ return (float)__builtin_bit_cast(_Float16,u); }
__device__ __forceinline__ float dot2f(u32 w, u32 x, float acc){
  return __builtin_amdgcn_fdot2(__builtin_bit_cast(half2_t,w), __builtin_bit_cast(half2_t,x), acc, false);
}
// DPP quad-permute moves (VALU-only cross-lane within quad)
__device__ __forceinline__ float qxor1(float x){
  return __builtin_bit_cast(float, __builtin_amdgcn_mov_dpp(__builtin_bit_cast(int,x), 0xB1, 0xf, 0xf, true)); // quad_perm(1,0,3,2)
}
__device__ __forceinline__ float qxor2(float x){
  return __builtin_bit_cast(float, __builtin_amdgcn_mov_dpp(__builtin_bit_cast(int,x), 0x4E, 0xf, 0xf, true)); // quad_perm(2,3,0,1)
}

// ---------- k_prep: blocks 0..103 compute Qp (= P @ W_m, f16 pairs); 104..359 compute M0W ----
__global__ __launch_bounds__(512)
void k_prep(const float* __restrict__ Wf, const float* __restrict__ Pf,
            const float* __restrict__ Wb, const float* __restrict__ Pb,
            const float* __restrict__ m0f, const float* __restrict__ m0b,
            u32* __restrict__ Qp, float* __restrict__ M0W)
{
  const int b = blockIdx.x, tid = threadIdx.x;
  if (b < 104){
    const int dir = b/52, j = b%52;
    const float* W = dir?Wb:Wf; const float* P = dir?Pb:Pf;
    __shared__ float pr[2][200];
    for (int i=tid;i<400;i+=512){ int u=i/200,k=i%200; int hk=2*j+u;
      pr[u][k] = (hk<100)? P[(size_t)hk*200+k] : 0.f; }
    __syncthreads();
    if (tid<400){
      float a0=0.f,a1=0.f;
      for (int k=0;k<200;++k){ float w = W[(size_t)(100+k)*400+tid]; a0 += pr[0][k]*w; a1 += pr[1][k]*w; }
      Qp[(size_t)(dir*52+j)*400+tid] = pk2(a0,a1);
    }
  } else {
    const int bb2 = b-104, dir = bb2>>7, seq = bb2&127;
    const float* m0 = dir?m0b:m0f; const float* W = dir?Wb:Wf;
    __shared__ float mr[200];
    if (tid<200) mr[tid] = m0[(size_t)seq*200+tid];
    __syncthreads();
    if (tid<400){
      float a=0.f;
      for (int k=0;k<200;++k) a += mr[k]*W[(size_t)(100+k)*400+tid];
      M0W[(size_t)bb2*400+tid] = a;
    }
  }
}

// ---------- k_g4: G = f16(x@Wx + bias(+1 f) [+ m0@Wm @ first t]) via MFMA (proven) ----------
__global__ __launch_bounds__(512, 1)
void k_g4(const float* __restrict__ z,
          const float* __restrict__ Wf, const float* __restrict__ bf,
          const float* __restrict__ Wb, const float* __restrict__ bb,
          const float* __restrict__ M0W, u16* __restrict__ Gh)
{
  __shared__ __align__(16) u16 xa[5][4][512];   // 5 M-tiles x 4 K-tiles, 20 KB
  const int tid = threadIdx.x, wv = tid>>6, lane = tid&63;
  const int l15 = lane&15, lg = lane>>4;
  const int dir = blockIdx.x>>7, seq = blockIdx.x&127;
  const float* W  = dir?Wb:Wf;
  const float* bv = dir?bb:bf;

  const int nnt = (wv==0)?4:3;
  const int ntl[4] = {wv, wv+8, wv+16, 24};

  f16x8 wb_[4][4];
  float bias[4], m0w[4];
  #pragma unroll
  for (int i=0;i<4;++i) if (i<nnt){
    const int col = ntl[i]*16 + l15;
    #pragma unroll
    for (int kt=0;kt<4;++kt){
      f16x8 v;
      #pragma unroll
      for (int e=0;e<8;++e){
        int k = kt*32 + lg*8 + e;
        v[e] = (_Float16)((k<100)? W[(size_t)k*400+col] : 0.f);
      }
      wb_[i][kt]=v;
    }
    bias[i] = bv[col] + (((col/100)==2)?1.0f:0.0f);
    m0w[i]  = M0W[(size_t)(dir*128+seq)*400 + col];
  }
  const int tfirst = dir?(TB-1):0;

  for (int i=tid;i<10240;i+=512) ((u16*)xa)[i] = (u16)0;
  __syncthreads();

  for (int chunk=0; chunk<5; ++chunk){
    for (int i=tid;i<8000;i+=512){
      int r = i/100, k = i%100;
      int t = chunk*80 + r;
      float v = z[(size_t)seq*40000 + (size_t)t*100 + k];
      int mt = r>>4, m = r&15, kt = k>>5, kk = k&31;
      xa[mt][kt][(m|((kk>>3)<<4))*8 + (kk&7)] = h16(v);
    }
    __syncthreads();
    #pragma unroll
    for (int mt=0; mt<5; ++mt){
      f16x8 af[4];
      #pragma unroll
      for (int kt=0;kt<4;++kt)
        af[kt] = *reinterpret_cast<const f16x8*>(&xa[mt][kt][lane*8]);
      #pragma unroll
      for (int i=0;i<4;++i) if (i<nnt){
        f32x4 acc = {0.f,0.f,0.f,0.f};
        #pragma unroll
        for (int kt=0;kt<4;++kt)
          acc = __builtin_amdgcn_mfma_f32_16x16x32_f16(af[kt], wb_[i][kt], acc, 0,0,0);
        const int col = ntl[i]*16 + l15;
        #pragma unroll
        for (int r=0;r<4;++r){
          int t = chunk*80 + mt*16 + lg*4 + r;
          float gv = acc[r] + bias[i] + ((t==tfirst)? m0w[i] : 0.f);
          Gh[((size_t)dir*51200 + (size_t)seq*400 + t)*400 + col] = h16(gv);
        }
      }
    }
    __syncthreads();
  }
}

// ---------- k_rec6: fused recurrence. gates (s,g)-quad + DPP exchange; proj lanes write out.
// 1 barrier/step, double-buffered h2. Loop t=0..TB: gates active t<TB, proj active t>=1 (m(t-1)).
__global__ __launch_bounds__(704, 1)
void k_rec6(const float* __restrict__ c0f, const float* __restrict__ c0b,
            const float* __restrict__ Pf, const float* __restrict__ Pb,
            const u32* __restrict__ Qp, const u16* __restrict__ Gh,
            float* __restrict__ out)
{
  __shared__ __align__(16) u32 h2[2][52];   // h f16-pairs; slots 50,51 = pad 0 (both parities)
  const int tid = threadIdx.x, dir = blockIdx.x>>7, seq = blockIdx.x&127;
  const float* c0 = dir?c0b:c0f;
  const float* P  = dir?Pb:Pf;
  const int s = tid>>2, g = tid&3;          // gates: cell s on quad, gate g (0:i 1:j 2:f 3:o)
  const int c = g*100 + s;

  uint4 wq[13];                             // gates Q column (52 u32, arch-VGPR resident)
  float cs = 0.f;
  if (tid < 400){
    #pragma unroll
    for (int q=0;q<13;++q){
      wq[q].x = Qp[(size_t)(dir*52+4*q+0)*400 + c];
      wq[q].y = Qp[(size_t)(dir*52+4*q+1)*400 + c];
      wq[q].z = Qp[(size_t)(dir*52+4*q+2)*400 + c];
      wq[q].w = Qp[(size_t)(dir*52+4*q+3)*400 + c];
    }
    cs = c0[(size_t)seq*100 + s];
  }
  const int pc = tid - 448;                 // proj: column pc in [0,200)
  uint4 pw[13];
  if (pc >= 0 && pc < 200){
    #pragma unroll
    for (int q=0;q<13;++q){
      u32 r[4];
      #pragma unroll
      for (int u=0;u<4;++u){
        int j = 4*q+u;
        r[u] = (j<50)? pk2(P[(size_t)(2*j)*200+pc], P[(size_t)(2*j+1)*200+pc]) : 0u;
      }
      pw[q] = make_uint4(r[0],r[1],r[2],r[3]);
    }
  }
  if (tid < 104) ((u32*)h2)[tid] = 0u;      // h(-1)=0; pads permanent
  __syncthreads();

  const u16* gptr = Gh + ((size_t)dir*51200 + (size_t)seq*400 + (dir?(TB-1):0))*400 + c;
  const intptr_t gstep = dir ? -400 : 400;
  u16 gn = 0;
  if (tid<400) gn = *gptr;

  for (int t=0; t<=TB; ++t){
    const int p = t&1;                      // h2[p] = h(t-1)
    if (tid < 400 && t < TB){
      u16 gc = gn;
      gptr += gstep;
      if (t+1 < TB) gn = *gptr;
      float a0=0.f,a1=0.f,a2=0.f,a3=0.f;
      #pragma unroll
      for (int q=0;q<13;++q){
        uint4 hv = *(const uint4*)(&h2[p][4*q]);
        a0=dot2f(wq[q].x,hv.x,a0); a1=dot2f(wq[q].y,hv.y,a1);
        a2=dot2f(wq[q].z,hv.z,a2); a3=dot2f(wq[q].w,hv.w,a3);
      }
      float a = ((a0+a1)+(a2+a3)) + f16f(gc);
      float arg = (g==1) ? a+a : a;         // tanh(x)=2*sig(2x)-1
      float v = sigf(arg);
      float act = (g==1) ? 2.0f*v-1.0f : v;
      float bx = qxor1(act);                // gate g^1
      float dx = qxor2(act);                // gate g^2
      float ex = qxor2(bx);                 // gate g^3
      float I = (g==0)?act:(g==1)?bx:(g==2)?dx:ex;
      float J = (g==1)?act:(g==0)?bx:(g==3)?dx:ex;
      float F = (g==2)?act:(g==3)?bx:(g==0)?dx:ex;
      float O = (g==3)?act:(g==2)?bx:(g==1)?dx:ex;
      float cc = F*cs + I*J; cs = cc;       // redundant x4, deterministic
      float h = O*tanhf_(cc);
      if (g==0) ((u16*)&h2[p^1][0])[s] = h16(h);
    } else if (pc >= 0 && pc < 200 && t >= 1){
      float m0=0.f,m1=0.f,m2=0.f,m3=0.f;
      #pragma unroll
      for (int q=0;q<13;++q){
        uint4 hv = *(const uint4*)(&h2[p][4*q]);
        m0=dot2f(pw[q].x,hv.x,m0); m1=dot2f(pw[q].y,hv.y,m1);
        m2=dot2f(pw[q].z,hv.z,m2); m3=dot2f(pw[q].w,hv.w,m3);
      }
      const int tt = dir ? (TB-t) : (t-1);  // orig time of step t-1
      __builtin_nontemporal_store((m0+m1)+(m2+m3),
          out + (size_t)seq*OUTROW + (size_t)tt*400 + dir*200 + pc);
    }
    __syncthreads();
  }
}

extern "C" void kernel_launch(void* const* d_in, const int* in_sizes, int n_in,
                              void* d_out, int out_size, void* d_ws, size_t ws_size,
                              hipStream_t stream) {
  (void)in_sizes; (void)n_in; (void)out_size; (void)ws_size;
  const float* z   = (const float*)d_in[0];
  const float* c0f = (const float*)d_in[1];
  const float* m0f = (const float*)d_in[2];
  const float* c0b = (const float*)d_in[3];
  const float* m0b = (const float*)d_in[4];
  const float* Wf  = (const float*)d_in[5];
  const float* bf  = (const float*)d_in[6];
  const float* Pf  = (const float*)d_in[7];
  const float* Wb  = (const float*)d_in[8];
  const float* bb  = (const float*)d_in[9];
  const float* Pb  = (const float*)d_in[10];

  u32*   Qp  = (u32*)d_ws;                            // 166,400 B
  float* M0W = (float*)((char*)d_ws + 196608);        // 409,600 B
  u16*   Gh  = (u16*)((char*)d_ws + 655360);          // 81,920,000 B (total ~82.6 MB)

  k_prep<<<360, 512, 0, stream>>>(Wf, Pf, Wb, Pb, m0f, m0b, Qp, M0W);
  k_g4  <<<256, 512, 0, stream>>>(z, Wf, bf, Wb, bb, M0W, Gh);
  k_rec6<<<256, 704, 0, stream>>>(c0f, c0b, Pf, Pb, Qp, Gh, (float*)d_out);
}